// Round 1
// baseline (308.916 us; speedup 1.0000x reference)
//
#include <hip/hip_runtime.h>

typedef __bf16 bf16x8 __attribute__((ext_vector_type(8)));
typedef float f32x4 __attribute__((ext_vector_type(4)));
typedef unsigned short u16;

#define GAS __attribute__((address_space(1)))
#define LAS __attribute__((address_space(3)))

static __device__ __forceinline__ void gload16(const void* g, void* l) {
  __builtin_amdgcn_global_load_lds((const GAS unsigned int*)g, (LAS unsigned int*)l, 16, 0, 0);
}

static __device__ __forceinline__ u16 f2bf(float f) {
  unsigned u = __builtin_bit_cast(unsigned, f);
  u += 0x7fffu + ((u >> 16) & 1u);
  return (u16)(u >> 16);
}

// ---------------- fp32 -> bf16 convert (vectorized) ----------------
__global__ void cvt_kernel(const float* __restrict__ src, u16* __restrict__ dst, int n4) {
  int i = blockIdx.x * 256 + threadIdx.x;
  if (i >= n4) return;
  float4 v = reinterpret_cast<const float4*>(src)[i];
  ushort4 o;
  o.x = f2bf(v.x); o.y = f2bf(v.y); o.z = f2bf(v.z); o.w = f2bf(v.w);
  reinterpret_cast<ushort4*>(dst)[i] = o;
}

// ---------------- QKV GEMM: C[8192x3072] = X[8192x1024] @ Wqkv^T ----------------
// 128x128 tile, BK=32, 4 waves (2x2), each wave 64x64 = 4x4 frags of 16x16x32.
// Epilogue scatters: Q (scaled 0.125) -> [B,H,S,64]; K -> [B,H,S,64]; V -> [B,H,64,S] (transposed).
__global__ void gemm_qkv(const u16* __restrict__ A, const u16* __restrict__ W,
                         u16* __restrict__ Qo, u16* __restrict__ Ko, u16* __restrict__ Vo) {
  __shared__ u16 As[128 * 32];
  __shared__ u16 Bs[128 * 32];
  const int t = threadIdx.x;
  const int lane = t & 63;
  const int w = t >> 6;
  const int wr = w >> 1, wc = w & 1;
  const int l15 = lane & 15, lhi = lane >> 4;
  const int bm = blockIdx.x / 24, bn = blockIdx.x % 24;

  f32x4 acc[4][4];
#pragma unroll
  for (int a = 0; a < 4; ++a)
#pragma unroll
    for (int b = 0; b < 4; ++b) acc[a][b] = (f32x4){0.f, 0.f, 0.f, 0.f};

  const u16* ag = A + (size_t)(bm * 128 + (t >> 2)) * 1024 + (t & 3) * 8;
  const u16* bg = W + (size_t)(bn * 128 + (t >> 2)) * 1024 + (t & 3) * 8;
  u16* as_p = &As[t * 8];
  u16* bs_p = &Bs[t * 8];

  for (int kt = 0; kt < 32; ++kt) {
    gload16(ag, as_p);
    gload16(ag + 64 * 1024, as_p + 2048);
    gload16(bg, bs_p);
    gload16(bg + 64 * 1024, bs_p + 2048);
    ag += 32; bg += 32;
    __syncthreads();
    bf16x8 af[4], bfr[4];
#pragma unroll
    for (int mt = 0; mt < 4; ++mt)
      af[mt] = *(const bf16x8*)&As[(wr * 64 + mt * 16 + l15) * 32 + lhi * 8];
#pragma unroll
    for (int nt = 0; nt < 4; ++nt)
      bfr[nt] = *(const bf16x8*)&Bs[(wc * 64 + nt * 16 + l15) * 32 + lhi * 8];
#pragma unroll
    for (int mt = 0; mt < 4; ++mt)
#pragma unroll
      for (int nt = 0; nt < 4; ++nt)
        acc[mt][nt] = __builtin_amdgcn_mfma_f32_16x16x32_bf16(af[mt], bfr[nt], acc[mt][nt], 0, 0, 0);
    __syncthreads();
  }

  // Epilogue. n in [0,3072): tsel = n>>10 block-uniform (bn/8); batch uniform (bm>>4).
  const int tsel = bn >> 3;
  const int m0 = bm * 128 + wr * 64;
  const int n0 = bn * 128 + wc * 64;
  const int bb = bm >> 4;  // batch index, uniform
  if (tsel == 0) {
#pragma unroll
    for (int nt = 0; nt < 4; ++nt) {
      int n = n0 + nt * 16 + l15;
      int c = n & 1023, h = c >> 6, hd = c & 63;
      size_t base = (size_t)(bb * 16 + h) * 2048 * 64 + hd;
#pragma unroll
      for (int mt = 0; mt < 4; ++mt)
#pragma unroll
        for (int i = 0; i < 4; ++i) {
          int s = (m0 + mt * 16 + lhi * 4 + i) & 2047;
          Qo[base + (size_t)s * 64] = f2bf(acc[mt][nt][i] * 0.125f);  // fold softmax scale
        }
    }
  } else if (tsel == 1) {
#pragma unroll
    for (int nt = 0; nt < 4; ++nt) {
      int n = n0 + nt * 16 + l15;
      int c = n & 1023, h = c >> 6, hd = c & 63;
      size_t base = (size_t)(bb * 16 + h) * 2048 * 64 + hd;
#pragma unroll
      for (int mt = 0; mt < 4; ++mt)
#pragma unroll
        for (int i = 0; i < 4; ++i) {
          int s = (m0 + mt * 16 + lhi * 4 + i) & 2047;
          Ko[base + (size_t)s * 64] = f2bf(acc[mt][nt][i]);
        }
    }
  } else {
    // V transposed: Vo[(pair*64 + hd)*2048 + s]; i=0..3 are consecutive s -> pack 8B store.
#pragma unroll
    for (int nt = 0; nt < 4; ++nt) {
      int n = n0 + nt * 16 + l15;
      int c = n & 1023, h = c >> 6, hd = c & 63;
#pragma unroll
      for (int mt = 0; mt < 4; ++mt) {
        int s0 = (m0 + mt * 16 + lhi * 4) & 2047;
        ushort4 pk;
        pk.x = f2bf(acc[mt][nt][0]);
        pk.y = f2bf(acc[mt][nt][1]);
        pk.z = f2bf(acc[mt][nt][2]);
        pk.w = f2bf(acc[mt][nt][3]);
        *(ushort4*)&Vo[((size_t)(bb * 16 + h) * 64 + hd) * 2048 + s0] = pk;
      }
    }
  }
}

// ---------------- Flash attention ----------------
// Grid 2048: bid = pair*32 + qtile. Block = 4 waves; wave owns 16 q-rows (QBLK=64).
// KV tile = 128. K LDS [128][64] swz; Vt LDS [64][128] swz; P LDS per-wave [16][128] swz.
// Swizzle: element column c stored at c ^ ((row&7)<<3)  (keeps 8-elem blocks contiguous,
// spreads the 16-lane row-parallel ds_read_b128 across all 32 banks).
__global__ void attn_kernel(const u16* __restrict__ Q, const u16* __restrict__ K,
                            const u16* __restrict__ Vt, u16* __restrict__ Ctx) {
  __shared__ u16 Ks[128 * 64];
  __shared__ u16 Vs[64 * 128];
  __shared__ u16 Ps[4 * 16 * 128];
  const int t = threadIdx.x;
  const int lane = t & 63;
  const int w = t >> 6;
  const int l15 = lane & 15, lhi = lane >> 4;
  const int bid = blockIdx.x;
  const int qt = bid & 31, pair = bid >> 5;
  const u16* qp = Q + (size_t)pair * 2048 * 64;
  const u16* kp = K + (size_t)pair * 2048 * 64;
  const u16* vp = Vt + (size_t)pair * 64 * 2048;

  // Q fragments stay in registers (A-operand: row = l15, k = lhi*8 + i, two K-steps)
  const int qrow = qt * 64 + w * 16 + l15;
  bf16x8 qf[2];
  qf[0] = *(const bf16x8*)&qp[(size_t)qrow * 64 + lhi * 8];
  qf[1] = *(const bf16x8*)&qp[(size_t)qrow * 64 + 32 + lhi * 8];

  float mrow[4] = {-1e30f, -1e30f, -1e30f, -1e30f};
  float lrow[4] = {0.f, 0.f, 0.f, 0.f};
  f32x4 co[4];
#pragma unroll
  for (int n = 0; n < 4; ++n) co[n] = (f32x4){0.f, 0.f, 0.f, 0.f};

  for (int kt = 0; kt < 16; ++kt) {
    // Stage K tile [128][64] (linear LDS dest, pre-swizzled global source)
#pragma unroll
    for (int j = 0; j < 4; ++j) {
      int r = j * 32 + (t >> 3);
      int c0 = (t & 7) * 8;
      gload16(kp + (size_t)(kt * 128 + r) * 64 + (c0 ^ ((r & 7) << 3)), &Ks[j * 2048 + t * 8]);
    }
    // Stage Vt tile [64][128]
#pragma unroll
    for (int j = 0; j < 4; ++j) {
      int r = j * 16 + (t >> 4);
      int c0 = (t & 15) * 8;
      gload16(vp + (size_t)r * 2048 + (size_t)kt * 128 + (c0 ^ ((r & 7) << 3)),
              &Vs[j * 2048 + t * 8]);
    }
    __syncthreads();

    // QK^T: S[16 x 128] per wave; 8 n-tiles x 2 k-steps
    f32x4 sa[8];
#pragma unroll
    for (int nt = 0; nt < 8; ++nt) {
      sa[nt] = (f32x4){0.f, 0.f, 0.f, 0.f};
#pragma unroll
      for (int ks = 0; ks < 2; ++ks) {
        int r = nt * 16 + l15;
        int c = (ks * 32 + lhi * 8) ^ ((r & 7) << 3);
        bf16x8 kf = *(const bf16x8*)&Ks[r * 64 + c];
        sa[nt] = __builtin_amdgcn_mfma_f32_16x16x32_bf16(qf[ks], kf, sa[nt], 0, 0, 0);
      }
    }

    // Online softmax. Row r = lhi*4+i; its 128 cols live in the 16 lanes of this lhi-group.
    float pscale[4];
#pragma unroll
    for (int i = 0; i < 4; ++i) {
      float mx = sa[0][i];
#pragma unroll
      for (int nt = 1; nt < 8; ++nt) mx = fmaxf(mx, sa[nt][i]);
      mx = fmaxf(mx, __shfl_xor(mx, 1));
      mx = fmaxf(mx, __shfl_xor(mx, 2));
      mx = fmaxf(mx, __shfl_xor(mx, 4));
      mx = fmaxf(mx, __shfl_xor(mx, 8));
      float mn = fmaxf(mrow[i], mx);
      float sc = __expf(mrow[i] - mn);
      float rs = 0.f;
#pragma unroll
      for (int nt = 0; nt < 8; ++nt) {
        float p = __expf(sa[nt][i] - mn);
        sa[nt][i] = p;
        rs += p;
      }
      rs += __shfl_xor(rs, 1);
      rs += __shfl_xor(rs, 2);
      rs += __shfl_xor(rs, 4);
      rs += __shfl_xor(rs, 8);
      lrow[i] = lrow[i] * sc + rs;
      mrow[i] = mn;
      pscale[i] = sc;
    }
#pragma unroll
    for (int nthd = 0; nthd < 4; ++nthd)
#pragma unroll
      for (int i = 0; i < 4; ++i) co[nthd][i] *= pscale[i];

    // Write P (D-layout -> LDS, swizzled)
#pragma unroll
    for (int nt = 0; nt < 8; ++nt)
#pragma unroll
      for (int i = 0; i < 4; ++i) {
        int r = lhi * 4 + i;
        int c = (l15 + nt * 16) ^ ((r & 7) << 3);
        Ps[w * 2048 + r * 128 + c] = f2bf(sa[nt][i]);
      }
    __syncthreads();

    // PV: ctx[16 x 64] += P[16 x 128] @ V[128 x 64]
    bf16x8 pf[4];
#pragma unroll
    for (int ks = 0; ks < 4; ++ks) {
      int c = (ks * 32 + lhi * 8) ^ ((l15 & 7) << 3);
      pf[ks] = *(const bf16x8*)&Ps[w * 2048 + l15 * 128 + c];
    }
#pragma unroll
    for (int nthd = 0; nthd < 4; ++nthd)
#pragma unroll
      for (int ks = 0; ks < 4; ++ks) {
        int r = nthd * 16 + l15;
        int c = (ks * 32 + lhi * 8) ^ ((r & 7) << 3);
        bf16x8 vf = *(const bf16x8*)&Vs[r * 128 + c];
        co[nthd] = __builtin_amdgcn_mfma_f32_16x16x32_bf16(pf[ks], vf, co[nthd], 0, 0, 0);
      }
    __syncthreads();
  }

  // Normalize and write ctx as [8192][1024] bf16 (row = b*2048+s, col = h*64+hd)
  const int bb = pair >> 4, h = pair & 15;
#pragma unroll
  for (int nthd = 0; nthd < 4; ++nthd)
#pragma unroll
    for (int i = 0; i < 4; ++i) {
      int s = qt * 64 + w * 16 + lhi * 4 + i;
      int hd = nthd * 16 + l15;
      float val = co[nthd][i] / lrow[i];
      Ctx[(size_t)(bb * 2048 + s) * 1024 + h * 64 + hd] = f2bf(val);
    }
}

// ---------------- Output GEMM: out[8192x1024] = Ctx @ Wo^T + bo (fp32 out) ----------------
__global__ void gemm_out(const u16* __restrict__ A, const u16* __restrict__ W,
                         const float* __restrict__ Bo, float* __restrict__ Out) {
  __shared__ u16 As[128 * 32];
  __shared__ u16 Bs[128 * 32];
  const int t = threadIdx.x;
  const int lane = t & 63;
  const int w = t >> 6;
  const int wr = w >> 1, wc = w & 1;
  const int l15 = lane & 15, lhi = lane >> 4;
  const int bm = blockIdx.x >> 3, bn = blockIdx.x & 7;

  f32x4 acc[4][4];
#pragma unroll
  for (int a = 0; a < 4; ++a)
#pragma unroll
    for (int b = 0; b < 4; ++b) acc[a][b] = (f32x4){0.f, 0.f, 0.f, 0.f};

  const u16* ag = A + (size_t)(bm * 128 + (t >> 2)) * 1024 + (t & 3) * 8;
  const u16* bg = W + (size_t)(bn * 128 + (t >> 2)) * 1024 + (t & 3) * 8;
  u16* as_p = &As[t * 8];
  u16* bs_p = &Bs[t * 8];

  for (int kt = 0; kt < 32; ++kt) {
    gload16(ag, as_p);
    gload16(ag + 64 * 1024, as_p + 2048);
    gload16(bg, bs_p);
    gload16(bg + 64 * 1024, bs_p + 2048);
    ag += 32; bg += 32;
    __syncthreads();
    bf16x8 af[4], bfr[4];
#pragma unroll
    for (int mt = 0; mt < 4; ++mt)
      af[mt] = *(const bf16x8*)&As[(wr * 64 + mt * 16 + l15) * 32 + lhi * 8];
#pragma unroll
    for (int nt = 0; nt < 4; ++nt)
      bfr[nt] = *(const bf16x8*)&Bs[(wc * 64 + nt * 16 + l15) * 32 + lhi * 8];
#pragma unroll
    for (int mt = 0; mt < 4; ++mt)
#pragma unroll
      for (int nt = 0; nt < 4; ++nt)
        acc[mt][nt] = __builtin_amdgcn_mfma_f32_16x16x32_bf16(af[mt], bfr[nt], acc[mt][nt], 0, 0, 0);
    __syncthreads();
  }

  const int m0 = bm * 128 + wr * 64;
  const int n0 = bn * 128 + wc * 64;
#pragma unroll
  for (int nt = 0; nt < 4; ++nt) {
    int n = n0 + nt * 16 + l15;
    float bias = Bo[n];
#pragma unroll
    for (int mt = 0; mt < 4; ++mt)
#pragma unroll
      for (int i = 0; i < 4; ++i) {
        int m = m0 + mt * 16 + lhi * 4 + i;
        Out[(size_t)m * 1024 + n] = acc[mt][nt][i] + bias;
      }
  }
}

// ---------------- launch ----------------
extern "C" void kernel_launch(void* const* d_in, const int* in_sizes, int n_in,
                              void* d_out, int out_size, void* d_ws, size_t ws_size,
                              hipStream_t stream) {
  const float* x  = (const float*)d_in[0];
  const float* wq = (const float*)d_in[1];
  const float* wk = (const float*)d_in[2];
  const float* wv = (const float*)d_in[3];
  const float* wo = (const float*)d_in[4];
  const float* bo = (const float*)d_in[5];
  float* out = (float*)d_out;

  // Workspace layout (bf16 elements). ctx aliases xb (xb dead after gemm_qkv).
  u16* xb    = (u16*)d_ws;                      // 8M
  u16* wqkvb = xb + (size_t)8 * 1024 * 1024;    // 3M
  u16* wob   = wqkvb + (size_t)3 * 1024 * 1024; // 1M
  u16* qb    = wob + (size_t)1 * 1024 * 1024;   // 8M
  u16* kb    = qb + (size_t)8 * 1024 * 1024;    // 8M
  u16* vtb   = kb + (size_t)8 * 1024 * 1024;    // 8M  -> total 36M elems = 72 MB
  u16* ctxb  = xb;                              // alias: safe, gemm_qkv done before attn

  cvt_kernel<<<8192, 256, 0, stream>>>(x, xb, 2097152);
  cvt_kernel<<<1024, 256, 0, stream>>>(wq, wqkvb, 262144);
  cvt_kernel<<<1024, 256, 0, stream>>>(wk, wqkvb + 1048576, 262144);
  cvt_kernel<<<1024, 256, 0, stream>>>(wv, wqkvb + 2097152, 262144);
  cvt_kernel<<<1024, 256, 0, stream>>>(wo, wob, 262144);
  gemm_qkv<<<64 * 24, 256, 0, stream>>>(xb, wqkvb, qb, kb, vtb);
  attn_kernel<<<2048, 256, 0, stream>>>(qb, kb, vtb, ctxb);
  gemm_out<<<64 * 8, 256, 0, stream>>>(ctxb, wob, bo, out);
}

// Round 2
// 293.329 us; speedup vs baseline: 1.0531x; 1.0531x over previous
//
#include <hip/hip_runtime.h>

typedef __bf16 bf16x8 __attribute__((ext_vector_type(8)));
typedef __bf16 bf16x4 __attribute__((ext_vector_type(4)));
typedef float f32x4 __attribute__((ext_vector_type(4)));
typedef unsigned u32x4 __attribute__((ext_vector_type(4)));
typedef unsigned short u16;

#define GAS __attribute__((address_space(1)))
#define LAS __attribute__((address_space(3)))

static __device__ __forceinline__ void gload16(const void* g, void* l) {
  __builtin_amdgcn_global_load_lds((const GAS unsigned int*)g, (LAS unsigned int*)l, 16, 0, 0);
}

static __device__ __forceinline__ u16 f2bf(float f) {
  unsigned u = __builtin_bit_cast(unsigned, f);
  u += 0x7fffu + ((u >> 16) & 1u);
  return (u16)(u >> 16);
}

// pack two f32 -> u32 of 2 bf16 (RNE); compiler pairs the casts into v_cvt_pk_bf16_f32
static __device__ __forceinline__ unsigned pk2(float lo, float hi) {
  ushort2 u;
  u.x = __builtin_bit_cast(u16, (__bf16)lo);
  u.y = __builtin_bit_cast(u16, (__bf16)hi);
  return __builtin_bit_cast(unsigned, u);
}

// ---------------- fp32 -> bf16 convert (vectorized) ----------------
__global__ void cvt_kernel(const float* __restrict__ src, u16* __restrict__ dst, int n4) {
  int i = blockIdx.x * 256 + threadIdx.x;
  if (i >= n4) return;
  float4 v = reinterpret_cast<const float4*>(src)[i];
  ushort4 o;
  o.x = f2bf(v.x); o.y = f2bf(v.y); o.z = f2bf(v.z); o.w = f2bf(v.w);
  reinterpret_cast<ushort4*>(dst)[i] = o;
}

// ---------------- QKV GEMM: C[8192x3072] = X[8192x1024] @ Wqkv^T ----------------
__global__ void gemm_qkv(const u16* __restrict__ A, const u16* __restrict__ W,
                         u16* __restrict__ Qo, u16* __restrict__ Ko, u16* __restrict__ Vo) {
  __shared__ u16 As[128 * 32];
  __shared__ u16 Bs[128 * 32];
  const int t = threadIdx.x;
  const int lane = t & 63;
  const int w = t >> 6;
  const int wr = w >> 1, wc = w & 1;
  const int l15 = lane & 15, lhi = lane >> 4;
  const int bm = blockIdx.x / 24, bn = blockIdx.x % 24;

  f32x4 acc[4][4];
#pragma unroll
  for (int a = 0; a < 4; ++a)
#pragma unroll
    for (int b = 0; b < 4; ++b) acc[a][b] = (f32x4){0.f, 0.f, 0.f, 0.f};

  const u16* ag = A + (size_t)(bm * 128 + (t >> 2)) * 1024 + (t & 3) * 8;
  const u16* bg = W + (size_t)(bn * 128 + (t >> 2)) * 1024 + (t & 3) * 8;
  u16* as_p = &As[t * 8];
  u16* bs_p = &Bs[t * 8];

  for (int kt = 0; kt < 32; ++kt) {
    gload16(ag, as_p);
    gload16(ag + 64 * 1024, as_p + 2048);
    gload16(bg, bs_p);
    gload16(bg + 64 * 1024, bs_p + 2048);
    ag += 32; bg += 32;
    __syncthreads();
    bf16x8 af[4], bfr[4];
#pragma unroll
    for (int mt = 0; mt < 4; ++mt)
      af[mt] = *(const bf16x8*)&As[(wr * 64 + mt * 16 + l15) * 32 + lhi * 8];
#pragma unroll
    for (int nt = 0; nt < 4; ++nt)
      bfr[nt] = *(const bf16x8*)&Bs[(wc * 64 + nt * 16 + l15) * 32 + lhi * 8];
#pragma unroll
    for (int mt = 0; mt < 4; ++mt)
#pragma unroll
      for (int nt = 0; nt < 4; ++nt)
        acc[mt][nt] = __builtin_amdgcn_mfma_f32_16x16x32_bf16(af[mt], bfr[nt], acc[mt][nt], 0, 0, 0);
    __syncthreads();
  }

  const int tsel = bn >> 3;
  const int m0 = bm * 128 + wr * 64;
  const int n0 = bn * 128 + wc * 64;
  const int bb = bm >> 4;
  if (tsel == 0) {
    // Q scaled by 1/sqrt(64) * log2(e) so attention softmax runs in exp2 domain
    const float qs = 0.125f * 1.4426950408889634f;
#pragma unroll
    for (int nt = 0; nt < 4; ++nt) {
      int n = n0 + nt * 16 + l15;
      int c = n & 1023, h = c >> 6, hd = c & 63;
      size_t base = (size_t)(bb * 16 + h) * 2048 * 64 + hd;
#pragma unroll
      for (int mt = 0; mt < 4; ++mt)
#pragma unroll
        for (int i = 0; i < 4; ++i) {
          int s = (m0 + mt * 16 + lhi * 4 + i) & 2047;
          Qo[base + (size_t)s * 64] = f2bf(acc[mt][nt][i] * qs);
        }
    }
  } else if (tsel == 1) {
#pragma unroll
    for (int nt = 0; nt < 4; ++nt) {
      int n = n0 + nt * 16 + l15;
      int c = n & 1023, h = c >> 6, hd = c & 63;
      size_t base = (size_t)(bb * 16 + h) * 2048 * 64 + hd;
#pragma unroll
      for (int mt = 0; mt < 4; ++mt)
#pragma unroll
        for (int i = 0; i < 4; ++i) {
          int s = (m0 + mt * 16 + lhi * 4 + i) & 2047;
          Ko[base + (size_t)s * 64] = f2bf(acc[mt][nt][i]);
        }
    }
  } else {
#pragma unroll
    for (int nt = 0; nt < 4; ++nt) {
      int n = n0 + nt * 16 + l15;
      int c = n & 1023, h = c >> 6, hd = c & 63;
#pragma unroll
      for (int mt = 0; mt < 4; ++mt) {
        int s0 = (m0 + mt * 16 + lhi * 4) & 2047;
        ushort4 pk;
        pk.x = f2bf(acc[mt][nt][0]);
        pk.y = f2bf(acc[mt][nt][1]);
        pk.z = f2bf(acc[mt][nt][2]);
        pk.w = f2bf(acc[mt][nt][3]);
        *(ushort4*)&Vo[((size_t)(bb * 16 + h) * 64 + hd) * 2048 + s0] = pk;
      }
    }
  }
}

// ---------------- Flash attention (swapped-QK, in-register softmax, shuffle-free PV) --------
// Grid 2048: bid = pair*32 + qtile. 4 waves; wave owns 16 q-rows. KV tile 128, double-buffered.
// Swapped QK^T: sa[nt] = mfma(K_frag, Q_frag) -> lane (l15,lhi) holds S[q=l15][kv=nt*16+lhi*4+i].
// PV uses sigma-permuted contraction: A-frag k-slot lhi*8+j <-> kv = ks*32+(j>>2)*16+lhi*4+(j&3),
// which is exactly the lane's own P values; V B-frag reads the matching kv rows (two b64 per frag).
__global__ void attn_kernel(const u16* __restrict__ Q, const u16* __restrict__ K,
                            const u16* __restrict__ Vt, u16* __restrict__ Ctx) {
  __shared__ u16 Ks[2][128 * 64];
  __shared__ u16 Vs[2][64 * 128];
  const int t = threadIdx.x;
  const int lane = t & 63;
  const int w = t >> 6;
  const int l15 = lane & 15, lhi = lane >> 4;
  const int qt = blockIdx.x & 31, pair = blockIdx.x >> 5;
  const u16* qp = Q + (size_t)pair * 2048 * 64;
  const u16* kp = K + (size_t)pair * 2048 * 64;
  const u16* vp = Vt + (size_t)pair * 64 * 2048;

  // Q fragment (B-operand of swapped QK: B[k=lhi*8+j][n=l15] = Q[q=l15][d])
  const int qrow = qt * 64 + w * 16 + l15;
  bf16x8 qf[2];
  qf[0] = *(const bf16x8*)&qp[(size_t)qrow * 64 + lhi * 8];
  qf[1] = *(const bf16x8*)&qp[(size_t)qrow * 64 + 32 + lhi * 8];

  float m = -1e30f, l = 0.f;
  f32x4 co[4];
#pragma unroll
  for (int n = 0; n < 4; ++n) co[n] = (f32x4){0.f, 0.f, 0.f, 0.f};

  auto stage = [&](int b, int tt) {
#pragma unroll
    for (int j = 0; j < 4; ++j) {
      int r = j * 32 + (t >> 3);
      int c0 = (t & 7) * 8;
      gload16(kp + (size_t)(tt * 128 + r) * 64 + (c0 ^ ((r & 7) << 3)), &Ks[b][j * 2048 + t * 8]);
    }
#pragma unroll
    for (int j = 0; j < 4; ++j) {
      int r = j * 16 + (t >> 4);
      int c0 = (t & 15) * 8;
      gload16(vp + (size_t)r * 2048 + tt * 128 + (c0 ^ ((r & 7) << 3)), &Vs[b][j * 2048 + t * 8]);
    }
  };

  stage(0, 0);
  __syncthreads();  // implicit vmcnt(0) drains staging

  for (int kt = 0; kt < 16; ++kt) {
    const int cur = kt & 1;
    if (kt < 15) stage(cur ^ 1, kt + 1);  // prefetch next tile into other buffer

    // ---- QK^T (swapped): A = K rows, B = Q ----
    f32x4 sa[8];
#pragma unroll
    for (int nt = 0; nt < 8; ++nt) {
      sa[nt] = (f32x4){0.f, 0.f, 0.f, 0.f};
#pragma unroll
      for (int ks = 0; ks < 2; ++ks) {
        int r = nt * 16 + l15;
        int c = (ks * 32 + lhi * 8) ^ ((r & 7) << 3);
        bf16x8 kf = *(const bf16x8*)&Ks[cur][r * 64 + c];
        sa[nt] = __builtin_amdgcn_mfma_f32_16x16x32_bf16(kf, qf[ks], sa[nt], 0, 0, 0);
      }
    }

    // ---- online softmax, fully in-lane (row q = l15), exp2 domain ----
    float mx = sa[0][0];
#pragma unroll
    for (int nt = 0; nt < 8; ++nt)
#pragma unroll
      for (int i = 0; i < 4; ++i) mx = fmaxf(mx, sa[nt][i]);
    mx = fmaxf(mx, __shfl_xor(mx, 16));
    mx = fmaxf(mx, __shfl_xor(mx, 32));

    float mn = m;
    if (!__all(mx - m <= 8.0f)) {  // defer-max: skip rescale when growth small
      mn = fmaxf(m, mx);
      float sc = __builtin_exp2f(m - mn);
      l *= sc;
      float si[4];
#pragma unroll
      for (int i = 0; i < 4; ++i) si[i] = __shfl(sc, lhi * 4 + i);
#pragma unroll
      for (int nthd = 0; nthd < 4; ++nthd)
#pragma unroll
        for (int i = 0; i < 4; ++i) co[nthd][i] *= si[i];
      m = mn;
    }

    float rs = 0.f;
#pragma unroll
    for (int nt = 0; nt < 8; ++nt)
#pragma unroll
      for (int i = 0; i < 4; ++i) {
        float p = __builtin_exp2f(sa[nt][i] - mn);
        sa[nt][i] = p;
        rs += p;
      }
    rs += __shfl_xor(rs, 16);
    rs += __shfl_xor(rs, 32);
    l += rs;

    // ---- pack P to bf16 in-register ----
    unsigned pw[8][2];
#pragma unroll
    for (int nt = 0; nt < 8; ++nt) {
      pw[nt][0] = pk2(sa[nt][0], sa[nt][1]);
      pw[nt][1] = pk2(sa[nt][2], sa[nt][3]);
    }

    // ---- PV: ctx[q][hd] += P[q][kv] V[kv][hd], sigma-permuted kv order ----
#pragma unroll
    for (int ks = 0; ks < 4; ++ks) {
      u32x4 aw = {pw[2 * ks][0], pw[2 * ks][1], pw[2 * ks + 1][0], pw[2 * ks + 1][1]};
      bf16x8 af = __builtin_bit_cast(bf16x8, aw);
#pragma unroll
      for (int nthd = 0; nthd < 4; ++nthd) {
        int row = nthd * 16 + l15;
        int swz = (row & 7) << 3;
        int c0 = (ks * 32 + lhi * 4) ^ swz;
        int c1 = (ks * 32 + 16 + lhi * 4) ^ swz;
        bf16x4 v0 = *(const bf16x4*)&Vs[cur][row * 128 + c0];
        bf16x4 v1 = *(const bf16x4*)&Vs[cur][row * 128 + c1];
        bf16x8 vf;
#pragma unroll
        for (int e = 0; e < 4; ++e) { vf[e] = v0[e]; vf[e + 4] = v1[e]; }
        co[nthd] = __builtin_amdgcn_mfma_f32_16x16x32_bf16(af, vf, co[nthd], 0, 0, 0);
      }
    }
    __syncthreads();  // drains prefetch (vmcnt 0) + all waves done reading cur
  }

  // ---- epilogue: normalize, write ctx [B*S][1024] bf16 ----
  float li[4];
#pragma unroll
  for (int i = 0; i < 4; ++i) li[i] = 1.0f / __shfl(l, lhi * 4 + i);
  const int bb = pair >> 4, h = pair & 15;
#pragma unroll
  for (int nthd = 0; nthd < 4; ++nthd)
#pragma unroll
    for (int i = 0; i < 4; ++i) {
      int s = qt * 64 + w * 16 + lhi * 4 + i;
      int hd = nthd * 16 + l15;
      Ctx[(size_t)(bb * 2048 + s) * 1024 + h * 64 + hd] = f2bf(co[nthd][i] * li[i]);
    }
}

// ---------------- Output GEMM: out[8192x1024] = Ctx @ Wo^T + bo (fp32 out) ----------------
__global__ void gemm_out(const u16* __restrict__ A, const u16* __restrict__ W,
                         const float* __restrict__ Bo, float* __restrict__ Out) {
  __shared__ u16 As[128 * 32];
  __shared__ u16 Bs[128 * 32];
  const int t = threadIdx.x;
  const int lane = t & 63;
  const int w = t >> 6;
  const int wr = w >> 1, wc = w & 1;
  const int l15 = lane & 15, lhi = lane >> 4;
  const int bm = blockIdx.x >> 3, bn = blockIdx.x & 7;

  f32x4 acc[4][4];
#pragma unroll
  for (int a = 0; a < 4; ++a)
#pragma unroll
    for (int b = 0; b < 4; ++b) acc[a][b] = (f32x4){0.f, 0.f, 0.f, 0.f};

  const u16* ag = A + (size_t)(bm * 128 + (t >> 2)) * 1024 + (t & 3) * 8;
  const u16* bg = W + (size_t)(bn * 128 + (t >> 2)) * 1024 + (t & 3) * 8;
  u16* as_p = &As[t * 8];
  u16* bs_p = &Bs[t * 8];

  for (int kt = 0; kt < 32; ++kt) {
    gload16(ag, as_p);
    gload16(ag + 64 * 1024, as_p + 2048);
    gload16(bg, bs_p);
    gload16(bg + 64 * 1024, bs_p + 2048);
    ag += 32; bg += 32;
    __syncthreads();
    bf16x8 af[4], bfr[4];
#pragma unroll
    for (int mt = 0; mt < 4; ++mt)
      af[mt] = *(const bf16x8*)&As[(wr * 64 + mt * 16 + l15) * 32 + lhi * 8];
#pragma unroll
    for (int nt = 0; nt < 4; ++nt)
      bfr[nt] = *(const bf16x8*)&Bs[(wc * 64 + nt * 16 + l15) * 32 + lhi * 8];
#pragma unroll
    for (int mt = 0; mt < 4; ++mt)
#pragma unroll
      for (int nt = 0; nt < 4; ++nt)
        acc[mt][nt] = __builtin_amdgcn_mfma_f32_16x16x32_bf16(af[mt], bfr[nt], acc[mt][nt], 0, 0, 0);
    __syncthreads();
  }

  const int m0 = bm * 128 + wr * 64;
  const int n0 = bn * 128 + wc * 64;
#pragma unroll
  for (int nt = 0; nt < 4; ++nt) {
    int n = n0 + nt * 16 + l15;
    float bias = Bo[n];
#pragma unroll
    for (int mt = 0; mt < 4; ++mt)
#pragma unroll
      for (int i = 0; i < 4; ++i) {
        int m = m0 + mt * 16 + lhi * 4 + i;
        Out[(size_t)m * 1024 + n] = acc[mt][nt][i] + bias;
      }
  }
}

// ---------------- launch ----------------
extern "C" void kernel_launch(void* const* d_in, const int* in_sizes, int n_in,
                              void* d_out, int out_size, void* d_ws, size_t ws_size,
                              hipStream_t stream) {
  const float* x  = (const float*)d_in[0];
  const float* wq = (const float*)d_in[1];
  const float* wk = (const float*)d_in[2];
  const float* wv = (const float*)d_in[3];
  const float* wo = (const float*)d_in[4];
  const float* bo = (const float*)d_in[5];
  float* out = (float*)d_out;

  u16* xb    = (u16*)d_ws;                      // 8M
  u16* wqkvb = xb + (size_t)8 * 1024 * 1024;    // 3M
  u16* wob   = wqkvb + (size_t)3 * 1024 * 1024; // 1M
  u16* qb    = wob + (size_t)1 * 1024 * 1024;   // 8M
  u16* kb    = qb + (size_t)8 * 1024 * 1024;    // 8M
  u16* vtb   = kb + (size_t)8 * 1024 * 1024;    // 8M
  u16* ctxb  = xb;                              // alias: xb dead after gemm_qkv

  cvt_kernel<<<8192, 256, 0, stream>>>(x, xb, 2097152);
  cvt_kernel<<<1024, 256, 0, stream>>>(wq, wqkvb, 262144);
  cvt_kernel<<<1024, 256, 0, stream>>>(wk, wqkvb + 1048576, 262144);
  cvt_kernel<<<1024, 256, 0, stream>>>(wv, wqkvb + 2097152, 262144);
  cvt_kernel<<<1024, 256, 0, stream>>>(wo, wob, 262144);
  gemm_qkv<<<64 * 24, 256, 0, stream>>>(xb, wqkvb, qb, kb, vtb);
  attn_kernel<<<2048, 256, 0, stream>>>(qb, kb, vtb, ctxb);
  gemm_out<<<64 * 8, 256, 0, stream>>>(ctxb, wob, bo, out);
}

// Round 3
// 249.572 us; speedup vs baseline: 1.2378x; 1.1753x over previous
//
#include <hip/hip_runtime.h>

typedef __bf16 bf16x8 __attribute__((ext_vector_type(8)));
typedef __bf16 bf16x4 __attribute__((ext_vector_type(4)));
typedef float f32x4 __attribute__((ext_vector_type(4)));
typedef unsigned u32x4 __attribute__((ext_vector_type(4)));
typedef unsigned short u16;

#define GAS __attribute__((address_space(1)))
#define LAS __attribute__((address_space(3)))

static __device__ __forceinline__ void gload16(const void* g, void* l) {
  __builtin_amdgcn_global_load_lds((const GAS unsigned int*)g, (LAS unsigned int*)l, 16, 0, 0);
}

static __device__ __forceinline__ u16 f2bf(float f) {
  unsigned u = __builtin_bit_cast(unsigned, f);
  u += 0x7fffu + ((u >> 16) & 1u);
  return (u16)(u >> 16);
}

static __device__ __forceinline__ unsigned pk2(float lo, float hi) {
  ushort2 u;
  u.x = __builtin_bit_cast(u16, (__bf16)lo);
  u.y = __builtin_bit_cast(u16, (__bf16)hi);
  return __builtin_bit_cast(unsigned, u);
}

static __device__ __forceinline__ f32x4 vmax4(f32x4 a, f32x4 b) {
  f32x4 r;
  r[0] = fmaxf(a[0], b[0]); r[1] = fmaxf(a[1], b[1]);
  r[2] = fmaxf(a[2], b[2]); r[3] = fmaxf(a[3], b[3]);
  return r;
}

// ---------------- fp32 -> bf16 converts ----------------
__global__ void cvt_kernel(const float* __restrict__ src, u16* __restrict__ dst, int n4) {
  int i = blockIdx.x * 256 + threadIdx.x;
  if (i >= n4) return;
  float4 v = reinterpret_cast<const float4*>(src)[i];
  ushort4 o;
  o.x = f2bf(v.x); o.y = f2bf(v.y); o.z = f2bf(v.z); o.w = f2bf(v.w);
  reinterpret_cast<ushort4*>(dst)[i] = o;
}

// all 4 weight matrices in one launch (1024 blocks each)
__global__ void cvt_w_kernel(const float* __restrict__ w0, const float* __restrict__ w1,
                             const float* __restrict__ w2, const float* __restrict__ w3,
                             u16* __restrict__ d0, u16* __restrict__ d1,
                             u16* __restrict__ d2, u16* __restrict__ d3) {
  int sel = blockIdx.x >> 10;
  int i = (blockIdx.x & 1023) * 256 + threadIdx.x;
  const float* s = sel == 0 ? w0 : sel == 1 ? w1 : sel == 2 ? w2 : w3;
  u16* d = sel == 0 ? d0 : sel == 1 ? d1 : sel == 2 ? d2 : d3;
  float4 v = reinterpret_cast<const float4*>(s)[i];
  ushort4 o;
  o.x = f2bf(v.x); o.y = f2bf(v.y); o.z = f2bf(v.z); o.w = f2bf(v.w);
  reinterpret_cast<ushort4*>(d)[i] = o;
}

// ---------------- QKV GEMM: C[8192x3072] = X[8192x1024] @ Wqkv^T ----------------
__global__ void gemm_qkv(const u16* __restrict__ A, const u16* __restrict__ W,
                         u16* __restrict__ Qo, u16* __restrict__ Ko, u16* __restrict__ Vo) {
  __shared__ u16 As[128 * 32];
  __shared__ u16 Bs[128 * 32];
  const int t = threadIdx.x;
  const int lane = t & 63;
  const int w = t >> 6;
  const int wr = w >> 1, wc = w & 1;
  const int l15 = lane & 15, lhi = lane >> 4;
  const int swz = (blockIdx.x & 7) * 192 + (blockIdx.x >> 3);  // XCD chunk (1536 = 8*192)
  const int bm = swz / 24, bn = swz % 24;

  f32x4 acc[4][4];
#pragma unroll
  for (int a = 0; a < 4; ++a)
#pragma unroll
    for (int b = 0; b < 4; ++b) acc[a][b] = (f32x4){0.f, 0.f, 0.f, 0.f};

  const u16* ag = A + (size_t)(bm * 128 + (t >> 2)) * 1024 + (t & 3) * 8;
  const u16* bg = W + (size_t)(bn * 128 + (t >> 2)) * 1024 + (t & 3) * 8;
  u16* as_p = &As[t * 8];
  u16* bs_p = &Bs[t * 8];

  for (int kt = 0; kt < 32; ++kt) {
    gload16(ag, as_p);
    gload16(ag + 64 * 1024, as_p + 2048);
    gload16(bg, bs_p);
    gload16(bg + 64 * 1024, bs_p + 2048);
    ag += 32; bg += 32;
    __syncthreads();
    bf16x8 af[4], bfr[4];
#pragma unroll
    for (int mt = 0; mt < 4; ++mt)
      af[mt] = *(const bf16x8*)&As[(wr * 64 + mt * 16 + l15) * 32 + lhi * 8];
#pragma unroll
    for (int nt = 0; nt < 4; ++nt)
      bfr[nt] = *(const bf16x8*)&Bs[(wc * 64 + nt * 16 + l15) * 32 + lhi * 8];
#pragma unroll
    for (int mt = 0; mt < 4; ++mt)
#pragma unroll
      for (int nt = 0; nt < 4; ++nt)
        acc[mt][nt] = __builtin_amdgcn_mfma_f32_16x16x32_bf16(af[mt], bfr[nt], acc[mt][nt], 0, 0, 0);
    __syncthreads();
  }

  const int tsel = bn >> 3;
  const int m0 = bm * 128 + wr * 64;
  const int n0 = bn * 128 + wc * 64;
  const int bb = bm >> 4;
  if (tsel == 0) {
    const float qs = 0.125f * 1.4426950408889634f;  // fold softmax scale + log2e
#pragma unroll
    for (int nt = 0; nt < 4; ++nt) {
      int n = n0 + nt * 16 + l15;
      int c = n & 1023, h = c >> 6, hd = c & 63;
      size_t base = (size_t)(bb * 16 + h) * 2048 * 64 + hd;
#pragma unroll
      for (int mt = 0; mt < 4; ++mt)
#pragma unroll
        for (int i = 0; i < 4; ++i) {
          int s = (m0 + mt * 16 + lhi * 4 + i) & 2047;
          Qo[base + (size_t)s * 64] = f2bf(acc[mt][nt][i] * qs);
        }
    }
  } else if (tsel == 1) {
#pragma unroll
    for (int nt = 0; nt < 4; ++nt) {
      int n = n0 + nt * 16 + l15;
      int c = n & 1023, h = c >> 6, hd = c & 63;
      size_t base = (size_t)(bb * 16 + h) * 2048 * 64 + hd;
#pragma unroll
      for (int mt = 0; mt < 4; ++mt)
#pragma unroll
        for (int i = 0; i < 4; ++i) {
          int s = (m0 + mt * 16 + lhi * 4 + i) & 2047;
          Ko[base + (size_t)s * 64] = f2bf(acc[mt][nt][i]);
        }
    }
  } else {
#pragma unroll
    for (int nt = 0; nt < 4; ++nt) {
      int n = n0 + nt * 16 + l15;
      int c = n & 1023, h = c >> 6, hd = c & 63;
#pragma unroll
      for (int mt = 0; mt < 4; ++mt) {
        int s0 = (m0 + mt * 16 + lhi * 4) & 2047;
        ushort4 pk;
        pk.x = f2bf(acc[mt][nt][0]);
        pk.y = f2bf(acc[mt][nt][1]);
        pk.z = f2bf(acc[mt][nt][2]);
        pk.w = f2bf(acc[mt][nt][3]);
        *(ushort4*)&Vo[((size_t)(bb * 16 + h) * 64 + hd) * 2048 + s0] = pk;
      }
    }
  }
}

// ---------------- Flash attention: QBLK=128 (2 q-frags per wave), KV tile 128 ----------------
// Swapped QK^T: sa = mfma(K, Q) -> lane(l15,lhi) holds S[q=l15][kv=nt*16+lhi*4+i].
// PV: sigma-permuted contraction, lane's own P values feed the A-frag; V from LDS b64 pairs.
__global__ __launch_bounds__(256, 2) void attn_kernel(const u16* __restrict__ Q,
                                                      const u16* __restrict__ K,
                                                      const u16* __restrict__ Vt,
                                                      u16* __restrict__ Ctx) {
  __shared__ u16 Ks[2][128 * 64];
  __shared__ u16 Vs[2][64 * 128];
  const int t = threadIdx.x;
  const int lane = t & 63;
  const int w = t >> 6;
  const int l15 = lane & 15, lhi = lane >> 4;
  const int swz = (blockIdx.x & 7) * 128 + (blockIdx.x >> 3);  // 1024 = 8*128, pair-locality per XCD
  const int qt = swz & 15, pair = swz >> 4;
  const u16* qp = Q + (size_t)pair * 2048 * 64;
  const u16* kp = K + (size_t)pair * 2048 * 64;
  const u16* vp = Vt + (size_t)pair * 64 * 2048;

  const int qrA = qt * 128 + w * 32 + l15;  // set A rows, set B = +16
  bf16x8 qfA[2], qfB[2];
  qfA[0] = *(const bf16x8*)&qp[(size_t)qrA * 64 + lhi * 8];
  qfA[1] = *(const bf16x8*)&qp[(size_t)qrA * 64 + 32 + lhi * 8];
  qfB[0] = *(const bf16x8*)&qp[(size_t)(qrA + 16) * 64 + lhi * 8];
  qfB[1] = *(const bf16x8*)&qp[(size_t)(qrA + 16) * 64 + 32 + lhi * 8];

  float mA = -1e30f, lA = 0.f, mB = -1e30f, lB = 0.f;
  f32x4 coA[4], coB[4];
#pragma unroll
  for (int n = 0; n < 4; ++n) { coA[n] = (f32x4){0.f, 0.f, 0.f, 0.f}; coB[n] = coA[n]; }

  auto stage = [&](int b, int tt) {
#pragma unroll
    for (int j = 0; j < 4; ++j) {
      int r = j * 32 + (t >> 3);
      int c0 = (t & 7) * 8;
      gload16(kp + (size_t)(tt * 128 + r) * 64 + (c0 ^ ((r & 7) << 3)), &Ks[b][j * 2048 + t * 8]);
    }
#pragma unroll
    for (int j = 0; j < 4; ++j) {
      int r = j * 16 + (t >> 4);
      int c0 = (t & 15) * 8;
      gload16(vp + (size_t)r * 2048 + tt * 128 + (c0 ^ ((r & 7) << 3)), &Vs[b][j * 2048 + t * 8]);
    }
  };

  auto softmax_step = [&](f32x4 (&sa)[8], float& m, float& l, f32x4 (&co)[4],
                          unsigned (&pw)[8][2]) {
    f32x4 t0 = vmax4(sa[0], sa[1]);
    f32x4 t1 = vmax4(sa[2], sa[3]);
    f32x4 t2 = vmax4(sa[4], sa[5]);
    f32x4 t3 = vmax4(sa[6], sa[7]);
    t0 = vmax4(t0, t1);
    t2 = vmax4(t2, t3);
    t0 = vmax4(t0, t2);
    float mx = fmaxf(fmaxf(t0[0], t0[1]), fmaxf(t0[2], t0[3]));
    mx = fmaxf(mx, __shfl_xor(mx, 16));
    mx = fmaxf(mx, __shfl_xor(mx, 32));
    float mn = m;
    if (!__all(mx - m <= 8.0f)) {  // defer-max (exp2 domain)
      mn = fmaxf(m, mx);
      float sc = __builtin_exp2f(m - mn);
      l *= sc;
      float si0 = __shfl(sc, lhi * 4 + 0);
      float si1 = __shfl(sc, lhi * 4 + 1);
      float si2 = __shfl(sc, lhi * 4 + 2);
      float si3 = __shfl(sc, lhi * 4 + 3);
#pragma unroll
      for (int nthd = 0; nthd < 4; ++nthd) {
        co[nthd][0] *= si0; co[nthd][1] *= si1;
        co[nthd][2] *= si2; co[nthd][3] *= si3;
      }
      m = mn;
    }
#pragma unroll
    for (int nt = 0; nt < 8; ++nt)
#pragma unroll
      for (int e = 0; e < 4; ++e) sa[nt][e] = __builtin_exp2f(sa[nt][e] - mn);
    f32x4 s0 = sa[0] + sa[1];
    f32x4 s1 = sa[2] + sa[3];
    f32x4 s2 = sa[4] + sa[5];
    f32x4 s3 = sa[6] + sa[7];
    s0 = s0 + s1; s2 = s2 + s3; s0 = s0 + s2;
    float rs = (s0[0] + s0[1]) + (s0[2] + s0[3]);
    rs += __shfl_xor(rs, 16);
    rs += __shfl_xor(rs, 32);
    l += rs;
#pragma unroll
    for (int nt = 0; nt < 8; ++nt) {
      pw[nt][0] = pk2(sa[nt][0], sa[nt][1]);
      pw[nt][1] = pk2(sa[nt][2], sa[nt][3]);
    }
  };

  stage(0, 0);
  __syncthreads();

  for (int kt = 0; kt < 16; ++kt) {
    const int cur = kt & 1;
    if (kt < 15) stage(cur ^ 1, kt + 1);

    // ---- QK^T (swapped), kf shared by both q-sets ----
    f32x4 saA[8], saB[8];
#pragma unroll
    for (int nt = 0; nt < 8; ++nt) {
      saA[nt] = (f32x4){0.f, 0.f, 0.f, 0.f};
      saB[nt] = saA[nt];
#pragma unroll
      for (int ks = 0; ks < 2; ++ks) {
        int r = nt * 16 + l15;
        int c = (ks * 32 + lhi * 8) ^ ((r & 7) << 3);
        bf16x8 kf = *(const bf16x8*)&Ks[cur][r * 64 + c];
        saA[nt] = __builtin_amdgcn_mfma_f32_16x16x32_bf16(kf, qfA[ks], saA[nt], 0, 0, 0);
        saB[nt] = __builtin_amdgcn_mfma_f32_16x16x32_bf16(kf, qfB[ks], saB[nt], 0, 0, 0);
      }
    }

    unsigned pwA[8][2], pwB[8][2];
    softmax_step(saA, mA, lA, coA, pwA);
    softmax_step(saB, mB, lB, coB, pwB);

    // ---- PV, vf shared by both q-sets ----
#pragma unroll
    for (int ks = 0; ks < 4; ++ks) {
      u32x4 awA = {pwA[2 * ks][0], pwA[2 * ks][1], pwA[2 * ks + 1][0], pwA[2 * ks + 1][1]};
      u32x4 awB = {pwB[2 * ks][0], pwB[2 * ks][1], pwB[2 * ks + 1][0], pwB[2 * ks + 1][1]};
      bf16x8 afA = __builtin_bit_cast(bf16x8, awA);
      bf16x8 afB = __builtin_bit_cast(bf16x8, awB);
#pragma unroll
      for (int nthd = 0; nthd < 4; ++nthd) {
        int row = nthd * 16 + l15;
        int swzr = (row & 7) << 3;
        int c0 = (ks * 32 + lhi * 4) ^ swzr;
        int c1 = (ks * 32 + 16 + lhi * 4) ^ swzr;
        bf16x4 v0 = *(const bf16x4*)&Vs[cur][row * 128 + c0];
        bf16x4 v1 = *(const bf16x4*)&Vs[cur][row * 128 + c1];
        bf16x8 vf;
#pragma unroll
        for (int e = 0; e < 4; ++e) { vf[e] = v0[e]; vf[e + 4] = v1[e]; }
        coA[nthd] = __builtin_amdgcn_mfma_f32_16x16x32_bf16(afA, vf, coA[nthd], 0, 0, 0);
        coB[nthd] = __builtin_amdgcn_mfma_f32_16x16x32_bf16(afB, vf, coB[nthd], 0, 0, 0);
      }
    }
    __syncthreads();
  }

  // ---- epilogue ----
  float liA[4], liB[4];
#pragma unroll
  for (int i = 0; i < 4; ++i) {
    liA[i] = 1.0f / __shfl(lA, lhi * 4 + i);
    liB[i] = 1.0f / __shfl(lB, lhi * 4 + i);
  }
  const int bb = pair >> 4, h = pair & 15;
  const int sbase = qt * 128 + w * 32 + lhi * 4;
#pragma unroll
  for (int nthd = 0; nthd < 4; ++nthd) {
    int hd = nthd * 16 + l15;
#pragma unroll
    for (int i = 0; i < 4; ++i) {
      Ctx[(size_t)(bb * 2048 + sbase + i) * 1024 + h * 64 + hd] = f2bf(coA[nthd][i] * liA[i]);
      Ctx[(size_t)(bb * 2048 + sbase + 16 + i) * 1024 + h * 64 + hd] = f2bf(coB[nthd][i] * liB[i]);
    }
  }
}

// ---------------- Output GEMM: out[8192x1024] = Ctx @ Wo^T + bo (fp32 out) ----------------
__global__ void gemm_out(const u16* __restrict__ A, const u16* __restrict__ W,
                         const float* __restrict__ Bo, float* __restrict__ Out) {
  __shared__ u16 As[128 * 32];
  __shared__ u16 Bs[128 * 32];
  const int t = threadIdx.x;
  const int lane = t & 63;
  const int w = t >> 6;
  const int wr = w >> 1, wc = w & 1;
  const int l15 = lane & 15, lhi = lane >> 4;
  const int swz = (blockIdx.x & 7) * 64 + (blockIdx.x >> 3);  // 512 = 8*64
  const int bm = swz >> 3, bn = swz & 7;

  f32x4 acc[4][4];
#pragma unroll
  for (int a = 0; a < 4; ++a)
#pragma unroll
    for (int b = 0; b < 4; ++b) acc[a][b] = (f32x4){0.f, 0.f, 0.f, 0.f};

  const u16* ag = A + (size_t)(bm * 128 + (t >> 2)) * 1024 + (t & 3) * 8;
  const u16* bg = W + (size_t)(bn * 128 + (t >> 2)) * 1024 + (t & 3) * 8;
  u16* as_p = &As[t * 8];
  u16* bs_p = &Bs[t * 8];

  for (int kt = 0; kt < 32; ++kt) {
    gload16(ag, as_p);
    gload16(ag + 64 * 1024, as_p + 2048);
    gload16(bg, bs_p);
    gload16(bg + 64 * 1024, bs_p + 2048);
    ag += 32; bg += 32;
    __syncthreads();
    bf16x8 af[4], bfr[4];
#pragma unroll
    for (int mt = 0; mt < 4; ++mt)
      af[mt] = *(const bf16x8*)&As[(wr * 64 + mt * 16 + l15) * 32 + lhi * 8];
#pragma unroll
    for (int nt = 0; nt < 4; ++nt)
      bfr[nt] = *(const bf16x8*)&Bs[(wc * 64 + nt * 16 + l15) * 32 + lhi * 8];
#pragma unroll
    for (int mt = 0; mt < 4; ++mt)
#pragma unroll
      for (int nt = 0; nt < 4; ++nt)
        acc[mt][nt] = __builtin_amdgcn_mfma_f32_16x16x32_bf16(af[mt], bfr[nt], acc[mt][nt], 0, 0, 0);
    __syncthreads();
  }

  const int m0 = bm * 128 + wr * 64;
  const int n0 = bn * 128 + wc * 64;
#pragma unroll
  for (int nt = 0; nt < 4; ++nt) {
    int n = n0 + nt * 16 + l15;
    float bias = Bo[n];
#pragma unroll
    for (int mt = 0; mt < 4; ++mt)
#pragma unroll
      for (int i = 0; i < 4; ++i) {
        int m = m0 + mt * 16 + lhi * 4 + i;
        Out[(size_t)m * 1024 + n] = acc[mt][nt][i] + bias;
      }
  }
}

// ---------------- launch ----------------
extern "C" void kernel_launch(void* const* d_in, const int* in_sizes, int n_in,
                              void* d_out, int out_size, void* d_ws, size_t ws_size,
                              hipStream_t stream) {
  const float* x  = (const float*)d_in[0];
  const float* wq = (const float*)d_in[1];
  const float* wk = (const float*)d_in[2];
  const float* wv = (const float*)d_in[3];
  const float* wo = (const float*)d_in[4];
  const float* bo = (const float*)d_in[5];
  float* out = (float*)d_out;

  u16* xb    = (u16*)d_ws;                      // 8M elems
  u16* wqkvb = xb + (size_t)8 * 1024 * 1024;    // 3M
  u16* wob   = wqkvb + (size_t)3 * 1024 * 1024; // 1M
  u16* qb    = wob + (size_t)1 * 1024 * 1024;   // 8M
  u16* kb    = qb + (size_t)8 * 1024 * 1024;    // 8M
  u16* vtb   = kb + (size_t)8 * 1024 * 1024;    // 8M
  u16* ctxb  = xb;                              // alias: xb dead after gemm_qkv

  cvt_kernel<<<8192, 256, 0, stream>>>(x, xb, 2097152);
  cvt_w_kernel<<<4096, 256, 0, stream>>>(wq, wk, wv, wo,
                                         wqkvb, wqkvb + 1048576, wqkvb + 2097152, wob);
  gemm_qkv<<<64 * 24, 256, 0, stream>>>(xb, wqkvb, qb, kb, vtb);
  attn_kernel<<<1024, 256, 0, stream>>>(qb, kb, vtb, ctxb);
  gemm_out<<<64 * 8, 256, 0, stream>>>(ctxb, wob, bo, out);
}